// Round 1
// 234.539 us; speedup vs baseline: 1.1196x; 1.1196x over previous
//
#include <hip/hip_runtime.h>
#include <hip/hip_bf16.h>

#define DPROJ 1024

typedef float  f32x4  __attribute__((ext_vector_type(4)));
typedef short  bf16x8 __attribute__((ext_vector_type(8)));

__device__ __forceinline__ unsigned pk2(float a, float b) {
    __hip_bfloat162 h = __float22bfloat162_rn(make_float2(a, b));
    unsigned r; __builtin_memcpy(&r, &h, 4); return r;
}

// async global->LDS, 16B per lane. LDS dest = wave-uniform base + lane*16.
__device__ __forceinline__ void gll16(const void* g, void* l) {
    __builtin_amdgcn_global_load_lds(
        (const __attribute__((address_space(1))) void*)g,
        (__attribute__((address_space(3))) void*)l, 16, 0, 0);
}

// ---------------- pass 1: parallel classify + proj->bf16 convert ------------
// Blocks [0, CB): classify n tokens, wave-aggregated atomicAdd compaction.
// List ORDER is nondeterministic but per-token output is bit-identical
// regardless of position (each row's dot products have fixed K-order).
// Blocks [CB, CB+680): convert the 4 proj tables fp32 -> bf16 (once/launch).
__global__ __launch_bounds__(256) void k_prep(
    const int* __restrict__ inp, int n,
    int* __restrict__ cnt, int* __restrict__ lists,
    const float* __restrict__ p0, const float* __restrict__ p1,
    const float* __restrict__ p2, const float* __restrict__ p3,
    short* __restrict__ pb0, short* __restrict__ pb1,
    short* __restrict__ pb2, short* __restrict__ pb3)
{
    const int tid = threadIdx.x;
    const int b   = blockIdx.x;
    const int CB  = (n + 255) >> 8;
    if (b < CB) {
        const int t = b * 256 + tid;
        int c = -1, l = 0;
        if (t < n) {
            const int x = inp[t];
            c = (x >= 20000) + (x >= 40000) + (x >= 200000);
            l = x - ((c == 0) ? 0 : (c == 1) ? 20000 : (c == 2) ? 40000 : 200000);
        }
        const int lane = tid & 63;
        int pos = 0;
        #pragma unroll
        for (int cc = 0; cc < 4; ++cc) {
            const unsigned long long mk = __ballot(c == cc);
            if (c == cc) {
                const int lead = __ffsll(mk) - 1;
                int base = 0;
                if (lane == lead) base = atomicAdd(&cnt[cc], (int)__popcll(mk));
                base = __shfl(base, lead);
                pos  = base + (int)__popcll(mk & ((1ull << lane) - 1ull));
            }
        }
        if (t < n) lists[c * n + pos] = (int)(((unsigned)t << 18) | (unsigned)l);
    } else {
        // chunk = 8 floats. counts: 131072 / 32768 / 8192 / 2048 (total 174080)
        const long g = (long)(b - CB) * 256 + tid;
        const float* src; short* dst; long lo;
        if      (g < 131072) { src = p0; dst = pb0; lo = g; }
        else if (g < 163840) { src = p1; dst = pb1; lo = g - 131072; }
        else if (g < 172032) { src = p2; dst = pb2; lo = g - 163840; }
        else if (g < 174080) { src = p3; dst = pb3; lo = g - 172032; }
        else return;
        const float4 a = *(const float4*)(src + lo * 8);
        const float4 c4 = *(const float4*)(src + lo * 8 + 4);
        uint4 q; q.x = pk2(a.x, a.y);   q.y = pk2(a.z, a.w);
                 q.z = pk2(c4.x, c4.y); q.w = pk2(c4.z, c4.w);
        *(uint4*)(dst + lo * 8) = q;
    }
}

// ---------------- pass 2: pipelined bf16-MFMA GEMM --------------------------
// SWAPPED operands: D = P(16 proj cols) x E^T(16 tokens) per MFMA, so each
// lane holds 4 CONSECUTIVE output cols of one token -> float4 stores.
// 2-phase pipeline: stage tile t+1 (E fp32->reg, P bf16 global_load_lds)
// before MFMA of tile t; one vmcnt(0)+barrier per K-step; dbuf LDS.
// P LDS layout: [kgroup 0..3][row 0..127][8 bf16] -> conflict-free b128 reads
// and linear in lane order for global_load_lds (wave w stages kgroup w).
__global__ __launch_bounds__(256, 4) void k_gemm(
    const int* __restrict__ cnt, const int* __restrict__ lists, int n,
    const float* __restrict__ e0, const float* __restrict__ e1,
    const float* __restrict__ e2, const float* __restrict__ e3,
    const short* __restrict__ pb0, const short* __restrict__ pb1,
    const short* __restrict__ pb2, const short* __restrict__ pb3,
    float* __restrict__ out)
{
    constexpr int TM = 64, TN = 128, KC = 32, ESTR = 40;

    const int z     = blockIdx.z;
    const int count = cnt[z];
    const int row0  = blockIdx.y * TM;
    if (row0 >= count) return;

    const float* emb = (z == 0) ? e0  : (z == 1) ? e1  : (z == 2) ? e2  : e3;
    const short* pb  = (z == 0) ? pb0 : (z == 1) ? pb1 : (z == 2) ? pb2 : pb3;
    const int    K   = (z == 0) ? 1024 : (z == 1) ? 256 : (z == 2) ? 64 : 16;
    const int*  list = lists + (size_t)z * n;
    const int   col0 = blockIdx.x * TN;

    __shared__ int   s_tok[TM];
    __shared__ int   s_loc[TM];
    __shared__ short e_s[2][TM * ESTR];     // 10240 B
    __shared__ short p_s[2][4 * TN * 8];    // 16384 B  [kgroup][row][8]

    const int tid = threadIdx.x;
    if (tid < TM) {
        int r = row0 + tid;
        if (r < count) {
            unsigned pk = (unsigned)list[r];
            s_tok[tid] = (int)(pk >> 18);
            s_loc[tid] = (int)(pk & 0x3FFFFu);
        } else { s_tok[tid] = -1; s_loc[tid] = -1; }
    }
    __syncthreads();

    const int wave = tid >> 6, lane = tid & 63;
    const int lm = lane & 15, quad = lane >> 4;

    // E staging role: 4 threads/row, 8 floats each
    const int erow = tid >> 2, egrp = tid & 3;
    const int eloc = s_loc[erow];
    const bool ev  = (eloc >= 0);
    const float* ebase = emb + (ev ? (size_t)eloc * K : 0) + egrp * 8;
    const int eoff = erow * ESTR + egrp * 8;
    short* ebuf = (short*)e_s;            // [2][TM*ESTR] flat
    short* pbuf = (short*)p_s;            // [2][4096] flat

    // P staging role: wave w stages kgroup w (k = w*8..w*8+7), 2 issues
    const short* pg0 = pb + (size_t)(col0 +      lane) * K + wave * 8;
    const short* pg1 = pb + (size_t)(col0 + 64 + lane) * K + wave * 8;
    const int pdoff0 = wave * 128 * 8;            // rows 0..63 of kgroup w
    const int pdoff1 = wave * 128 * 8 + 64 * 8;   // rows 64..127

    f32x4 acc[8];
    #pragma unroll
    for (int i = 0; i < 8; ++i) acc[i] = (f32x4){0.f, 0.f, 0.f, 0.f};

    const int nt = (K + KC - 1) / KC;     // 32 / 8 / 2 / 1
    float ef[8];

    // ---- prologue: stage tile 0 into buf 0
    {
        const bool v = ev && (egrp * 8 < K);
        if (v) {
            float4 a = *(const float4*)(ebase);
            float4 b = *(const float4*)(ebase + 4);
            ef[0] = a.x; ef[1] = a.y; ef[2] = a.z; ef[3] = a.w;
            ef[4] = b.x; ef[5] = b.y; ef[6] = b.z; ef[7] = b.w;
        } else {
            #pragma unroll
            for (int j = 0; j < 8; ++j) ef[j] = 0.f;
        }
        gll16(pg0, pbuf + pdoff0);
        gll16(pg1, pbuf + pdoff1);
        uint4 q; q.x = pk2(ef[0], ef[1]); q.y = pk2(ef[2], ef[3]);
                 q.z = pk2(ef[4], ef[5]); q.w = pk2(ef[6], ef[7]);
        *(uint4*)(ebuf + eoff) = q;
    }
    __syncthreads();

    for (int t = 0; t < nt; ++t) {
        const int  cur = t & 1;
        const int  kn  = (t + 1) * KC;
        const bool pf  = (kn < K);
        if (pf) {   // issue next tile's loads BEFORE compute (T3 2-phase)
            const bool v = ev && (kn + egrp * 8 < K);
            if (v) {
                const float* s = ebase + kn;
                float4 a = *(const float4*)(s);
                float4 b = *(const float4*)(s + 4);
                ef[0] = a.x; ef[1] = a.y; ef[2] = a.z; ef[3] = a.w;
                ef[4] = b.x; ef[5] = b.y; ef[6] = b.z; ef[7] = b.w;
            } else {
                #pragma unroll
                for (int j = 0; j < 8; ++j) ef[j] = 0.f;
            }
            const int nb = (cur ^ 1) * 4096;
            gll16(pg0 + kn, pbuf + nb + pdoff0);
            gll16(pg1 + kn, pbuf + nb + pdoff1);
        }

        // frags + MFMA on buf[cur]
        bf16x8 ebf = *(const bf16x8*)(ebuf + cur * (TM * ESTR)
                                      + (wave * 16 + lm) * ESTR + quad * 8);
        const short* pk_ = pbuf + cur * 4096 + quad * (TN * 8) + lm * 8;
        #pragma unroll
        for (int ns = 0; ns < 8; ++ns) {
            bf16x8 pfr = *(const bf16x8*)(pk_ + ns * 128);
            acc[ns] = __builtin_amdgcn_mfma_f32_16x16x32_bf16(pfr, ebf, acc[ns], 0, 0, 0);
        }

        if (pf) {   // convert+write E for next tile (HBM latency hid under MFMA)
            uint4 q; q.x = pk2(ef[0], ef[1]); q.y = pk2(ef[2], ef[3]);
                     q.z = pk2(ef[4], ef[5]); q.w = pk2(ef[6], ef[7]);
            *(uint4*)(ebuf + (cur ^ 1) * (TM * ESTR) + eoff) = q;
        }
        __syncthreads();   // compiler drains vmcnt/lgkmcnt here: buf[cur^1] ready
    }

    // epilogue: lane = token lm, 4 consecutive cols per reg -> float4 NT stores
    const int tok = s_tok[wave * 16 + lm];
    if (tok >= 0) {
        float* orow = out + (size_t)tok * DPROJ + col0 + quad * 4;
        #pragma unroll
        for (int ns = 0; ns < 8; ++ns) {
            f32x4 v = acc[ns] * 32.f;
            __builtin_nontemporal_store(v, (f32x4*)(orow + ns * 16));
        }
    }
}

extern "C" void kernel_launch(void* const* d_in, const int* in_sizes, int n_in,
                              void* d_out, int out_size, void* d_ws, size_t ws_size,
                              hipStream_t stream) {
    const int*   inp = (const int*)d_in[0];
    const float* e0  = (const float*)d_in[1];
    const float* p0  = (const float*)d_in[2];
    const float* e1  = (const float*)d_in[3];
    const float* p1  = (const float*)d_in[4];
    const float* e2  = (const float*)d_in[5];
    const float* p2  = (const float*)d_in[6];
    const float* e3  = (const float*)d_in[7];
    const float* p3  = (const float*)d_in[8];
    float* out = (float*)d_out;
    const int n = in_sizes[0];  // 16384 tokens

    // ws layout: cnt[4] | lists[4n] | pb0 | pb1 | pb3 | pb2   (~3.05 MB)
    // pb3 deliberately NOT last: z=3 (K=16 < KC) global_load_lds overshoots
    // by <=48B into pb2's (finite bf16) data, which multiplies staged E zeros.
    char* wsb  = (char*)d_ws;
    int* cnt   = (int*)wsb;
    int* lists = (int*)(wsb + 16);
    size_t off = 16 + (size_t)4 * n * sizeof(int);
    off = (off + 255) & ~(size_t)255;
    short* pb0 = (short*)(wsb + off); off += (size_t)1024 * 1024 * 2;
    short* pb1 = (short*)(wsb + off); off += (size_t)1024 * 256 * 2;
    short* pb3 = (short*)(wsb + off); off += (size_t)1024 * 16 * 2;
    short* pb2 = (short*)(wsb + off); off += (size_t)1024 * 64 * 2;

    hipMemsetAsync(cnt, 0, 4 * sizeof(int), stream);

    const int CB = (n + 255) >> 8;
    k_prep<<<CB + 680, 256, 0, stream>>>(inp, n, cnt, lists,
                                         p0, p1, p2, p3, pb0, pb1, pb2, pb3);

    dim3 grid(DPROJ / 128, (n + 63) / 64, 4);
    k_gemm<<<grid, 256, 0, stream>>>(cnt, lists, n, e0, e1, e2, e3,
                                     pb0, pb1, pb2, pb3, out);
}

// Round 2
// 228.451 us; speedup vs baseline: 1.1494x; 1.0267x over previous
//
#include <hip/hip_runtime.h>
#include <hip/hip_bf16.h>

#define DPROJ 1024

typedef float  f32x4  __attribute__((ext_vector_type(4)));
typedef short  bf16x8 __attribute__((ext_vector_type(8)));

__device__ __forceinline__ unsigned pk2(float a, float b) {
    __hip_bfloat162 h = __float22bfloat162_rn(make_float2(a, b));
    unsigned r; __builtin_memcpy(&r, &h, 4); return r;
}

// async global->LDS, 16B per lane. LDS dest = wave-uniform base + lane*16.
__device__ __forceinline__ void gll16(const void* g, void* l) {
    __builtin_amdgcn_global_load_lds(
        (const __attribute__((address_space(1))) void*)g,
        (__attribute__((address_space(3))) void*)l, 16, 0, 0);
}

// ---------------- pass 1: classify + proj->bf16 convert ---------------------
// Blocks [0, CB): classify n tokens (wave-aggregated atomic compaction; list
// order nondeterministic but per-token output is order-independent).
// Blocks [CB, CB+688): convert proj tables fp32 -> bf16. pb3 is written with
// row stride 32 (k 16..31 zero-padded) so k_gemm's uniform KC=32 loop never
// reads out of bounds for z=3.
__global__ __launch_bounds__(256) void k_prep(
    const int* __restrict__ inp, int n,
    int* __restrict__ cnt, int* __restrict__ lists,
    const float* __restrict__ p0, const float* __restrict__ p1,
    const float* __restrict__ p2, const float* __restrict__ p3,
    short* __restrict__ pb0, short* __restrict__ pb1,
    short* __restrict__ pb2, short* __restrict__ pb3)
{
    const int tid = threadIdx.x;
    const int b   = blockIdx.x;
    const int CB  = (n + 255) >> 8;
    if (b < CB) {
        const int t = b * 256 + tid;
        int c = -1, l = 0;
        if (t < n) {
            const int x = inp[t];
            c = (x >= 20000) + (x >= 40000) + (x >= 200000);
            l = x - ((c == 0) ? 0 : (c == 1) ? 20000 : (c == 2) ? 40000 : 200000);
        }
        const int lane = tid & 63;
        int pos = 0;
        #pragma unroll
        for (int cc = 0; cc < 4; ++cc) {
            const unsigned long long mk = __ballot(c == cc);
            if (c == cc) {
                const int lead = __ffsll(mk) - 1;
                int base = 0;
                if (lane == lead) base = atomicAdd(&cnt[cc], (int)__popcll(mk));
                base = __shfl(base, lead);
                pos  = base + (int)__popcll(mk & ((1ull << lane) - 1ull));
            }
        }
        if (t < n) lists[c * n + pos] = (int)(((unsigned)t << 18) | (unsigned)l);
    } else {
        // chunk = 8 floats. pb0:131072  pb1:32768  pb2:8192  pb3:4096(padded)
        const long g = (long)(b - CB) * 256 + tid;
        if (g < 172032) {
            const float* src; short* dst; long lo;
            if      (g < 131072) { src = p0; dst = pb0; lo = g; }
            else if (g < 163840) { src = p1; dst = pb1; lo = g - 131072; }
            else                 { src = p2; dst = pb2; lo = g - 163840; }
            const float4 a = *(const float4*)(src + lo * 8);
            const float4 d = *(const float4*)(src + lo * 8 + 4);
            uint4 q; q.x = pk2(a.x, a.y); q.y = pk2(a.z, a.w);
                     q.z = pk2(d.x, d.y); q.w = pk2(d.z, d.w);
            *(uint4*)(dst + lo * 8) = q;
        } else if (g < 176128) {
            const long lo = g - 172032;           // 0..4095
            const int col = (int)(lo >> 2), c = (int)(lo & 3);
            uint4 q = (uint4){0u, 0u, 0u, 0u};
            if (c < 2) {
                const float* src = p3 + (size_t)col * 16 + c * 8;
                const float4 a = *(const float4*)src;
                const float4 d = *(const float4*)(src + 4);
                q.x = pk2(a.x, a.y); q.y = pk2(a.z, a.w);
                q.z = pk2(d.x, d.y); q.w = pk2(d.z, d.w);
            }
            *(uint4*)(pb3 + (size_t)col * 32 + c * 8) = q;
        }
    }
}

// ---------------- pass 2: gather used E rows -> compact bf16 ----------------
// ec layout: cluster-contiguous, row r of cluster z at ec + off_z + r*Kpad
// (Kpad = 1024/256/64/32; z=3 zero-padded k 16..31). Within each 32-k block
// the 16B groups are stored XOR-swizzled by ((r>>1)&3) so k_gemm's linear
// global_load_lds + XOR'd ds_read_b128 is 2-way-bank-conflict-free (rule 21:
// pre-swizzled source, swizzled read). Chunk = 16B (8 bf16).
__global__ __launch_bounds__(256) void k_egather(
    const int* __restrict__ cnt, const int* __restrict__ lists, int n,
    const float* __restrict__ e0, const float* __restrict__ e1,
    const float* __restrict__ e2, const float* __restrict__ e3,
    short* __restrict__ ec)
{
    const int c0 = cnt[0], c1 = cnt[1], c2 = cnt[2], c3 = cnt[3];
    const long t0 = (long)c0 * 128;          // chunks/row: 128, 32, 8, 4
    const long t1 = t0 + (long)c1 * 32;
    const long t2 = t1 + (long)c2 * 8;
    const long t3 = t2 + (long)c3 * 4;
    const long o1 = (long)c0 * 1024;         // ec offsets in shorts
    const long o2 = o1 + (long)c1 * 256;
    const long o3 = o2 + (long)c2 * 64;

    const long stride = (long)gridDim.x * 256;
    for (long i = (long)blockIdx.x * 256 + threadIdx.x; i < t3; i += stride) {
        int z, Kp, Kr, lc; long rem, off; const float* emb;
        if (i < t0)      { z = 0; rem = i;      off = 0;  emb = e0; Kp = 1024; Kr = 1024; lc = 7; }
        else if (i < t1) { z = 1; rem = i - t0; off = o1; emb = e1; Kp = 256;  Kr = 256;  lc = 5; }
        else if (i < t2) { z = 2; rem = i - t1; off = o2; emb = e2; Kp = 64;   Kr = 64;   lc = 3; }
        else             { z = 3; rem = i - t2; off = o3; emb = e3; Kp = 32;   Kr = 16;   lc = 2; }
        const int r = (int)(rem >> lc);
        const int c = (int)(rem & ((1 << lc) - 1));
        const int k = c * 8;
        uint4 q = (uint4){0u, 0u, 0u, 0u};
        if (k < Kr) {
            const int loc = lists[z * n + r] & 0x3FFFF;
            const float* src = emb + (size_t)loc * Kr + k;
            const float4 a = *(const float4*)src;
            const float4 d = *(const float4*)(src + 4);
            q.x = pk2(a.x, a.y); q.y = pk2(a.z, a.w);
            q.z = pk2(d.x, d.y); q.w = pk2(d.z, d.w);
        }
        const int gsw = (c & ~3) | ((c ^ ((r >> 1) & 3)) & 3);
        *(uint4*)(ec + off + (size_t)r * Kp + gsw * 8) = q;
    }
}

// ---------------- pass 3: bf16-MFMA GEMM ------------------------------------
// Grid launched as (y, z, x) with y FASTEST: the 8 col-blocks of one (y,z)
// have linear ids spaced by gridDim.x*gridDim.y = 1024 == 0 (mod 8 XCDs), so
// they land on the SAME XCD and share its L2 copy of the 64 E rows (was the
// 8x E over-fetch). All staging is global_load_lds bf16 (no VALU cvt in loop).
// Swapped MFMA (A=P, B=E): lane holds 4 consecutive out cols of one token ->
// plain float4 stores (NT dropped: it defeated L2 64B-half merging, +25MB).
__global__ __launch_bounds__(256, 6) void k_gemm(
    const int* __restrict__ cnt, const int* __restrict__ lists, int n,
    const short* __restrict__ ec,
    const short* __restrict__ pb0, const short* __restrict__ pb1,
    const short* __restrict__ pb2, const short* __restrict__ pb3,
    float* __restrict__ out)
{
    const int yb = blockIdx.x, z = blockIdx.y, xb = blockIdx.z;
    const int count = cnt[z];
    const int row0  = yb * 64;
    if (row0 >= count) return;

    const int c0 = cnt[0], c1 = cnt[1], c2 = cnt[2];
    const short* pb = (z == 0) ? pb0 : (z == 1) ? pb1 : (z == 2) ? pb2 : pb3;
    const int    Kp = (z == 0) ? 1024 : (z == 1) ? 256 : (z == 2) ? 64 : 32;
    const long eoff = (z == 0) ? 0
                    : (z == 1) ? (long)c0 * 1024
                    : (z == 2) ? (long)c0 * 1024 + (long)c1 * 256
                               : (long)c0 * 1024 + (long)c1 * 256 + (long)c2 * 64;
    const short* ecz  = ec + eoff;
    const int    nt   = Kp >> 5;
    const int    col0 = xb * 128;
    const int*   list = lists + (size_t)z * n;

    __shared__ int   s_tok[64];
    __shared__ short e_s[2][64 * 32];      //  8 KiB total
    __shared__ short p_s[2][4 * 128 * 8];  // 16 KiB total

    const int tid = threadIdx.x;
    if (tid < 64) {
        const int r = row0 + tid;
        s_tok[tid] = (r < count) ? (int)((unsigned)list[r] >> 18) : -1;
    }

    const int wave = tid >> 6, lane = tid & 63;
    const int lm = lane & 15, quad = lane >> 4;

    // E staging: wave w owns rows [w*16, w*16+16); lane l -> row w*16+l/4,
    // 16B group l&3 (copies the stored swizzled bytes LINEARLY).
    const short* esrc = ecz + (size_t)(row0 + wave * 16 + (lane >> 2)) * Kp
                            + (lane & 3) * 8;
    short* eb   = &e_s[0][0];                 // buf stride 2048 shorts
    const int edst = wave * 512;              // shorts within buf

    // P staging: wave w stages k-group w; 2 issues (cols 0..63, 64..127).
    const short* psrc0 = pb + (size_t)(col0 +      lane) * Kp + wave * 8;
    const short* psrc1 = pb + (size_t)(col0 + 64 + lane) * Kp + wave * 8;
    short* pbuf_ = &p_s[0][0];                // buf stride 4096 shorts
    const int pdst = wave * 1024;

    // ds_read addresses (shorts within buf)
    const int eread = (wave * 16 + lm) * 32 + (quad ^ ((lm >> 1) & 3)) * 8;
    const int pread = quad * 1024 + lm * 8;

    f32x4 acc[8];
    #pragma unroll
    for (int i = 0; i < 8; ++i) acc[i] = (f32x4){0.f, 0.f, 0.f, 0.f};

    // prologue: stage tile 0 into buf 0 (also covers the s_tok barrier)
    gll16(esrc,  eb    + edst);
    gll16(psrc0, pbuf_ + pdst);
    gll16(psrc1, pbuf_ + pdst + 512);
    __syncthreads();

    for (int t = 0; t < nt; ++t) {
        const int cur = t & 1;
        if (t + 1 < nt) {                    // issue next tile BEFORE compute
            const int kb = (t + 1) * 32;
            const int nb = cur ^ 1;
            gll16(esrc  + kb, eb    + nb * 2048 + edst);
            gll16(psrc0 + kb, pbuf_ + nb * 4096 + pdst);
            gll16(psrc1 + kb, pbuf_ + nb * 4096 + pdst + 512);
        }
        const bf16x8 ebf = *(const bf16x8*)(eb + cur * 2048 + eread);
        const short* pk_ = pbuf_ + cur * 4096 + pread;
        #pragma unroll
        for (int ns = 0; ns < 8; ++ns) {
            bf16x8 pfr = *(const bf16x8*)(pk_ + ns * 128);
            acc[ns] = __builtin_amdgcn_mfma_f32_16x16x32_bf16(pfr, ebf, acc[ns], 0, 0, 0);
        }
        __syncthreads();                     // drains gll16s for buf cur^1
    }

    // epilogue: D col = token (lane&15), D row = proj col quad*4+reg
    const int tok = s_tok[wave * 16 + lm];
    if (tok >= 0) {
        float* orow = out + (size_t)tok * DPROJ + col0 + quad * 4;
        #pragma unroll
        for (int ns = 0; ns < 8; ++ns) {
            f32x4 v = acc[ns] * 32.f;
            *(f32x4*)(orow + ns * 16) = v;
        }
    }
}

extern "C" void kernel_launch(void* const* d_in, const int* in_sizes, int n_in,
                              void* d_out, int out_size, void* d_ws, size_t ws_size,
                              hipStream_t stream) {
    const int*   inp = (const int*)d_in[0];
    const float* e0  = (const float*)d_in[1];
    const float* p0  = (const float*)d_in[2];
    const float* e1  = (const float*)d_in[3];
    const float* p1  = (const float*)d_in[4];
    const float* e2  = (const float*)d_in[5];
    const float* p2  = (const float*)d_in[6];
    const float* e3  = (const float*)d_in[7];
    const float* p3  = (const float*)d_in[8];
    float* out = (float*)d_out;
    const int n = in_sizes[0];  // 16384 tokens

    // ws: cnt[4] | lists[4n] | pb0..pb3 (pb3 stride-32 padded) | ec (compact E)
    char* wsb  = (char*)d_ws;
    int* cnt   = (int*)wsb;
    int* lists = (int*)(wsb + 16);
    size_t off = 16 + (size_t)4 * n * sizeof(int);
    off = (off + 255) & ~(size_t)255;
    short* pb0 = (short*)(wsb + off); off += (size_t)1024 * 1024 * 2;
    short* pb1 = (short*)(wsb + off); off += (size_t)1024 * 256 * 2;
    short* pb2 = (short*)(wsb + off); off += (size_t)1024 * 64 * 2;
    short* pb3 = (short*)(wsb + off); off += (size_t)1024 * 32 * 2;
    short* ec  = (short*)(wsb + off);   // worst case n*1024 bf16 = 32 MB;
                                        // actual ~4.7 MB for this distribution

    hipMemsetAsync(cnt, 0, 4 * sizeof(int), stream);

    const int CB = (n + 255) >> 8;
    k_prep<<<CB + 688, 256, 0, stream>>>(inp, n, cnt, lists,
                                         p0, p1, p2, p3, pb0, pb1, pb2, pb3);
    k_egather<<<1024, 256, 0, stream>>>(cnt, lists, n, e0, e1, e2, e3, ec);

    dim3 grid((n + 63) / 64, 4, 8);     // (y, z, x): y fastest -> XCD co-location
    k_gemm<<<grid, 256, 0, stream>>>(cnt, lists, n, ec,
                                     pb0, pb1, pb2, pb3, out);
}